// Round 5
// baseline (211.315 us; speedup 1.0000x reference)
//
#include <hip/hip_runtime.h>
#include <hip/hip_bf16.h>
#include <stdint.h>

typedef __attribute__((ext_vector_type(8))) short  vshort8;
typedef __attribute__((ext_vector_type(4))) float  vfloat4;
typedef __attribute__((ext_vector_type(4))) int    vint4;

static constexpr int Bb   = 8;
static constexpr int Nn   = 1024;
static constexpr int FIN  = 512;
static constexpr int FOUT = 512;
static constexpr int Hh   = 8;
static constexpr int DH   = 64;
static constexpr int Mm   = Bb * Nn;          // 8192
static constexpr float LRELU_ALPHA = 0.2f;

__device__ __forceinline__ unsigned short f2bf(float f) {
  union { float f; uint32_t u; } c; c.f = f;
  uint32_t r = c.u + 0x7fffu + ((c.u >> 16) & 1u);   // RNE
  return (unsigned short)(r >> 16);
}
__device__ __forceinline__ float bf2f(unsigned short s) {
  union { uint32_t u; float f; } c; c.u = ((uint32_t)s) << 16; return c.f;
}

// ---------------- K1: cast x -> bf16 (into d_out scratch) ----------------
__global__ __launch_bounds__(256) void cast_x_kernel(const float* __restrict__ x,
                                                     short* __restrict__ xb, int n) {
  int i = (blockIdx.x * 256 + threadIdx.x) * 8;
  const int stride = gridDim.x * 256 * 8;
  for (; i < n; i += stride) {
    vfloat4 v0 = *(const vfloat4*)(x + i);
    vfloat4 v1 = *(const vfloat4*)(x + i + 4);
    vshort8 o;
    o[0] = (short)f2bf(v0[0]); o[1] = (short)f2bf(v0[1]);
    o[2] = (short)f2bf(v0[2]); o[3] = (short)f2bf(v0[3]);
    o[4] = (short)f2bf(v1[0]); o[5] = (short)f2bf(v1[1]);
    o[6] = (short)f2bf(v1[2]); o[7] = (short)f2bf(v1[3]);
    *(vshort8*)(xb + i) = o;
  }
}

// ---------------- K1b: W[k][n] -> Wt[n][k] bf16 (into d_out scratch) ------
__global__ __launch_bounds__(256) void transpose_w_kernel(const float* __restrict__ W,
                                                          short* __restrict__ Wt) {
  __shared__ float tile[64 * 65];
  const int n0 = blockIdx.x * 64, k0 = blockIdx.y * 64;
  const int c = threadIdx.x & 63, r4 = threadIdx.x >> 6;
  #pragma unroll
  for (int rr = 0; rr < 64; rr += 4)
    tile[(rr + r4) * 65 + c] = W[(size_t)(k0 + rr + r4) * FOUT + n0 + c];
  __syncthreads();
  #pragma unroll
  for (int rr = 0; rr < 64; rr += 4)
    Wt[(size_t)(n0 + rr + r4) * FIN + k0 + c] = (short)f2bf(tile[c * 65 + rr + r4]);
}

// ---------------- K2: hbt[b,h,d,n] = (xb @ W + bias)^T via swapped MFMA ---
__global__ __launch_bounds__(256) void gemm_t_kernel(const short* __restrict__ A,
                                                     const short* __restrict__ Bt,
                                                     const float* __restrict__ bias,
                                                     short* __restrict__ hbt) {
  __shared__ short As[128 * 64];
  __shared__ short Bs[128 * 64];
  const int tid = threadIdx.x;
  const int w = tid >> 6, l = tid & 63;
  const int wv = w >> 1;   // fout half of block tile
  const int wu = w & 1;    // m half of block tile
  const int lrow = l & 15, lk = l >> 4;
  const int m0 = blockIdx.x * 128, n0 = blockIdx.y * 128;
  vfloat4 acc[4][4] = {};
  for (int kt = 0; kt < FIN; kt += 64) {
    #pragma unroll
    for (int itr = 0; itr < 4; ++itr) {
      const int e = w * 2048 + itr * 512 + l * 8;
      const int row = e >> 6, col = e & 63;
      __builtin_amdgcn_global_load_lds(
          (const __attribute__((address_space(1))) unsigned int*)(A + (size_t)(m0 + row) * FIN + kt + col),
          (__attribute__((address_space(3))) unsigned int*)(As + w * 2048 + itr * 512),
          16, 0, 0);
      __builtin_amdgcn_global_load_lds(
          (const __attribute__((address_space(1))) unsigned int*)(Bt + (size_t)(n0 + row) * FIN + kt + col),
          (__attribute__((address_space(3))) unsigned int*)(Bs + w * 2048 + itr * 512),
          16, 0, 0);
    }
    __syncthreads();
    #pragma unroll
    for (int ks = 0; ks < 2; ++ks) {
      vshort8 af[4], bfr[4];
      #pragma unroll
      for (int i = 0; i < 4; ++i)   // A-operand of MFMA = Wt rows (fout dim)
        af[i] = *(const vshort8*)(Bs + (wv * 64 + i * 16 + lrow) * 64 + ks * 32 + lk * 8);
      #pragma unroll
      for (int j = 0; j < 4; ++j)   // B-operand of MFMA = x rows (m dim)
        bfr[j] = *(const vshort8*)(As + (wu * 64 + j * 16 + lrow) * 64 + ks * 32 + lk * 8);
      #pragma unroll
      for (int i = 0; i < 4; ++i)
        #pragma unroll
        for (int j = 0; j < 4; ++j)
          acc[i][j] = __builtin_amdgcn_mfma_f32_16x16x32_bf16(af[i], bfr[j], acc[i][j], 0, 0, 0);
    }
    __syncthreads();
  }
  // D layout: row (lk*4+r) = fout-local, col (lrow) = m-local  -> direct hbt write
  #pragma unroll
  for (int i = 0; i < 4; ++i) {
    const int fbase = n0 + wv * 64 + i * 16 + lk * 4;
    const vfloat4 bv = *(const vfloat4*)(bias + fbase);
    #pragma unroll
    for (int r = 0; r < 4; ++r) {
      const int fg = fbase + r;
      const int h = fg >> 6, d = fg & 63;
      #pragma unroll
      for (int j = 0; j < 4; ++j) {
        const int mg = m0 + wu * 64 + j * 16 + lrow;
        const int b = mg >> 10, n = mg & 1023;
        hbt[((size_t)(b * Hh + h) * DH + d) * Nn + n] = (short)f2bf(acc[i][j][r] + bv[r]);
      }
    }
  }
}

// ---------------- K3: s_src/s_dst from hbt ----------------
__global__ __launch_bounds__(256) void scores_kernel(const short* __restrict__ hbt,
                                                     const float* __restrict__ att,
                                                     float* __restrict__ ssrc,
                                                     float* __restrict__ sdst) {
  const int bh = blockIdx.y;                 // b*8 + h
  const int h = bh & 7;
  const int n = blockIdx.x * 256 + threadIdx.x;
  const short* base = hbt + (size_t)bh * DH * Nn + n;
  const float* as_ = att + h * 2 * DH;
  const float* ad_ = as_ + DH;
  float ps = 0.f, pd = 0.f;
  #pragma unroll
  for (int d = 0; d < DH; ++d) {
    const float v = bf2f((unsigned short)base[(size_t)d * Nn]);
    ps += v * as_[d];
    pd += v * ad_[d];
  }
  ssrc[(size_t)bh * Nn + n] = ps;
  sdst[(size_t)bh * Nn + n] = pd;
}

// ---------------- K4: fused masked-softmax attention + PV + ELU ----------------
// 8 waves: waves 0-3 own j in [0,512), waves 4-7 own j in [512,1024) for the
// same 64 query rows; partial acc/denoms combined through LDS.
__global__ __launch_bounds__(512) void attn_kernel(const int* __restrict__ adj,
                                                   const float* __restrict__ ssrc,
                                                   const float* __restrict__ sdst,
                                                   const short* __restrict__ hbt,
                                                   float* __restrict__ out) {
  __shared__ vfloat4 laccs[4][4][64];   // [df][iw][lane]
  __shared__ float   lsum[4][64];
  const int it = blockIdx.x, h = blockIdx.y, b = blockIdx.z;
  const int tid = threadIdx.x;
  const int w = tid >> 6, l = tid & 63;
  const int iw = w & 3, jg = w >> 2;
  const int lrow = l & 15, lk = l >> 4;
  const int i = it * 64 + iw * 16 + lrow;          // query row owned by this lane
  const float sdi = sdst[(size_t)(b * Hh + h) * Nn + i];
  const float* ssp = ssrc + (size_t)(b * Hh + h) * Nn;
  const int* adjrow = adj + ((size_t)b * Nn + i) * Nn;
  const short* vb = hbt + (size_t)(b * Hh + h) * DH * Nn;
  vfloat4 acc[4] = {};
  float dsum = 0.f;
  const int jbeg = jg * 512, jend = jbeg + 512;
  for (int j0 = jbeg; j0 < jend; j0 += 32) {
    const int jb = j0 + lk * 8;
    vfloat4 s0 = *(const vfloat4*)(ssp + jb);
    vfloat4 s1 = *(const vfloat4*)(ssp + jb + 4);
    const vint4 a0 = __builtin_nontemporal_load((const vint4*)(adjrow + jb));
    const vint4 a1 = __builtin_nontemporal_load((const vint4*)(adjrow + jb + 4));
    const float sv[8] = {s0[0], s0[1], s0[2], s0[3], s1[0], s1[1], s1[2], s1[3]};
    const int   av[8] = {a0[0], a0[1], a0[2], a0[3], a1[0], a1[1], a1[2], a1[3]};
    vshort8 af;
    #pragma unroll
    for (int e = 0; e < 8; ++e) {
      float tv = sdi + sv[e];
      tv = fmaxf(tv, LRELU_ALPHA * tv);              // leaky_relu, alpha<1
      const float pe = (av[e] > 0) ? __expf(tv) : 0.f; // exp w/o max-sub: logits bounded ~9
      const unsigned short pb = f2bf(pe);
      af[e] = (short)pb;
      dsum += bf2f(pb);                              // denom consistent with bf16 numerator
    }
    vshort8 bfr[4];
    #pragma unroll
    for (int df = 0; df < 4; ++df)
      bfr[df] = *(const vshort8*)(vb + (size_t)(df * 16 + lrow) * Nn + jb);
    #pragma unroll
    for (int df = 0; df < 4; ++df)
      acc[df] = __builtin_amdgcn_mfma_f32_16x16x32_bf16(af, bfr[df], acc[df], 0, 0, 0);
  }
  if (jg == 1) {
    #pragma unroll
    for (int df = 0; df < 4; ++df) laccs[df][iw][l] = acc[df];
    lsum[iw][l] = dsum;
  }
  __syncthreads();
  if (jg == 1) return;
  #pragma unroll
  for (int df = 0; df < 4; ++df) acc[df] = acc[df] + laccs[df][iw][l];
  dsum += lsum[iw][l];
  dsum += __shfl_xor(dsum, 16);
  dsum += __shfl_xor(dsum, 32);
  #pragma unroll
  for (int r = 0; r < 4; ++r) {
    const int lr = lk * 4 + r;                       // local output row (C/D layout)
    const float den = __shfl(dsum, lr);
    const float inv = 1.0f / den;
    const int row = it * 64 + iw * 16 + lr;
    #pragma unroll
    for (int df = 0; df < 4; ++df) {
      float v = acc[df][r] * inv;
      v = v > 0.f ? v : expm1f(v);                   // ELU (alpha=1)
      out[((size_t)(b * Nn + row)) * FOUT + h * DH + df * 16 + lrow] = v;
    }
  }
}

extern "C" void kernel_launch(void* const* d_in, const int* in_sizes, int n_in,
                              void* d_out, int out_size, void* d_ws, size_t ws_size,
                              hipStream_t stream) {
  const float* x   = (const float*)d_in[0];
  const int*   adj = (const int*)d_in[1];
  const float* W   = (const float*)d_in[2];
  const float* Wb  = (const float*)d_in[3];
  const float* att = (const float*)d_in[4];
  float* out = (float*)d_out;

  // Scratch plan:
  //   d_out (16 MB, fully overwritten by attn_kernel at the end):
  //     [0, 8 MB)   xb  = bf16 cast of x            (dead after gemm)
  //     [8, 8.5 MB) Wt  = bf16 W^T [fout][fin]      (dead after gemm)
  //   d_ws (8.5 MB used — stays well inside workspace):
  //     [0, 8 MB)   hbt = (x@W+b)^T as [b][h][d][n] bf16
  //     [8, 8.5 MB) ssrc, sdst (f32)
  short* xb  = (short*)d_out;
  short* Wt  = xb + (size_t)Mm * FIN;
  short* hbt = (short*)d_ws;
  float* ssrc = (float*)(hbt + (size_t)Bb * Hh * DH * Nn);
  float* sdst = ssrc + (size_t)Bb * Hh * Nn;

  cast_x_kernel<<<1024, 256, 0, stream>>>(x, xb, Mm * FIN);
  transpose_w_kernel<<<dim3(FOUT / 64, FIN / 64), 256, 0, stream>>>(W, Wt);
  gemm_t_kernel<<<dim3(Mm / 128, FOUT / 128), 256, 0, stream>>>(xb, Wt, Wb, hbt);
  scores_kernel<<<dim3(Nn / 256, Bb * Hh), 256, 0, stream>>>(hbt, att, ssrc, sdst);
  attn_kernel<<<dim3(Nn / 64, Hh, Bb), 512, 0, stream>>>(adj, ssrc, sdst, hbt, out);
}

// Round 6
// 207.517 us; speedup vs baseline: 1.0183x; 1.0183x over previous
//
#include <hip/hip_runtime.h>
#include <hip/hip_bf16.h>
#include <stdint.h>

typedef __attribute__((ext_vector_type(8))) short  vshort8;
typedef __attribute__((ext_vector_type(4))) float  vfloat4;
typedef __attribute__((ext_vector_type(4))) int    vint4;

static constexpr int Bb   = 8;
static constexpr int Nn   = 1024;
static constexpr int FIN  = 512;
static constexpr int FOUT = 512;
static constexpr int Hh   = 8;
static constexpr int DH   = 64;
static constexpr int Mm   = Bb * Nn;          // 8192
static constexpr float LRELU_ALPHA = 0.2f;

__device__ __forceinline__ unsigned short f2bf(float f) {
  union { float f; uint32_t u; } c; c.f = f;
  uint32_t r = c.u + 0x7fffu + ((c.u >> 16) & 1u);   // RNE
  return (unsigned short)(r >> 16);
}
__device__ __forceinline__ float bf2f(unsigned short s) {
  union { uint32_t u; float f; } c; c.u = ((uint32_t)s) << 16; return c.f;
}

// ---------------- K1: cast x -> bf16 (into d_out scratch) ----------------
__global__ __launch_bounds__(256) void cast_x_kernel(const float* __restrict__ x,
                                                     short* __restrict__ xb, int n) {
  int i = (blockIdx.x * 256 + threadIdx.x) * 8;
  const int stride = gridDim.x * 256 * 8;
  for (; i < n; i += stride) {
    vfloat4 v0 = *(const vfloat4*)(x + i);
    vfloat4 v1 = *(const vfloat4*)(x + i + 4);
    vshort8 o;
    o[0] = (short)f2bf(v0[0]); o[1] = (short)f2bf(v0[1]);
    o[2] = (short)f2bf(v0[2]); o[3] = (short)f2bf(v0[3]);
    o[4] = (short)f2bf(v1[0]); o[5] = (short)f2bf(v1[1]);
    o[6] = (short)f2bf(v1[2]); o[7] = (short)f2bf(v1[3]);
    *(vshort8*)(xb + i) = o;
  }
}

// ---------------- K1b: W[k][n] -> Wt[n][k] bf16 (into d_out scratch) ------
__global__ __launch_bounds__(256) void transpose_w_kernel(const float* __restrict__ W,
                                                          short* __restrict__ Wt) {
  __shared__ float tile[64 * 65];
  const int n0 = blockIdx.x * 64, k0 = blockIdx.y * 64;
  const int c = threadIdx.x & 63, r4 = threadIdx.x >> 6;
  #pragma unroll
  for (int rr = 0; rr < 64; rr += 4)
    tile[(rr + r4) * 65 + c] = W[(size_t)(k0 + rr + r4) * FOUT + n0 + c];
  __syncthreads();
  #pragma unroll
  for (int rr = 0; rr < 64; rr += 4)
    Wt[(size_t)(n0 + rr + r4) * FIN + k0 + c] = (short)f2bf(tile[c * 65 + rr + r4]);
}

// ---------------- K2: hbt[b,h,d,n] = (xb @ W + bias)^T via swapped MFMA ---
__global__ __launch_bounds__(256) void gemm_t_kernel(const short* __restrict__ A,
                                                     const short* __restrict__ Bt,
                                                     const float* __restrict__ bias,
                                                     short* __restrict__ hbt) {
  __shared__ short As[128 * 64];
  __shared__ short Bs[128 * 64];
  const int tid = threadIdx.x;
  const int w = tid >> 6, l = tid & 63;
  const int wv = w >> 1;   // fout half of block tile
  const int wu = w & 1;    // m half of block tile
  const int lrow = l & 15, lk = l >> 4;
  const int m0 = blockIdx.x * 128, n0 = blockIdx.y * 128;
  vfloat4 acc[4][4] = {};
  for (int kt = 0; kt < FIN; kt += 64) {
    #pragma unroll
    for (int itr = 0; itr < 4; ++itr) {
      const int e = w * 2048 + itr * 512 + l * 8;
      const int row = e >> 6, col = e & 63;
      __builtin_amdgcn_global_load_lds(
          (const __attribute__((address_space(1))) unsigned int*)(A + (size_t)(m0 + row) * FIN + kt + col),
          (__attribute__((address_space(3))) unsigned int*)(As + w * 2048 + itr * 512),
          16, 0, 0);
      __builtin_amdgcn_global_load_lds(
          (const __attribute__((address_space(1))) unsigned int*)(Bt + (size_t)(n0 + row) * FIN + kt + col),
          (__attribute__((address_space(3))) unsigned int*)(Bs + w * 2048 + itr * 512),
          16, 0, 0);
    }
    __syncthreads();
    #pragma unroll
    for (int ks = 0; ks < 2; ++ks) {
      vshort8 af[4], bfr[4];
      #pragma unroll
      for (int i = 0; i < 4; ++i)   // A-operand of MFMA = Wt rows (fout dim)
        af[i] = *(const vshort8*)(Bs + (wv * 64 + i * 16 + lrow) * 64 + ks * 32 + lk * 8);
      #pragma unroll
      for (int j = 0; j < 4; ++j)   // B-operand of MFMA = x rows (m dim)
        bfr[j] = *(const vshort8*)(As + (wu * 64 + j * 16 + lrow) * 64 + ks * 32 + lk * 8);
      #pragma unroll
      for (int i = 0; i < 4; ++i)
        #pragma unroll
        for (int j = 0; j < 4; ++j)
          acc[i][j] = __builtin_amdgcn_mfma_f32_16x16x32_bf16(af[i], bfr[j], acc[i][j], 0, 0, 0);
    }
    __syncthreads();
  }
  // D layout: row (lk*4+r) = fout-local, col (lrow) = m-local  -> direct hbt write
  #pragma unroll
  for (int i = 0; i < 4; ++i) {
    const int fbase = n0 + wv * 64 + i * 16 + lk * 4;
    const vfloat4 bv = *(const vfloat4*)(bias + fbase);
    #pragma unroll
    for (int r = 0; r < 4; ++r) {
      const int fg = fbase + r;
      const int h = fg >> 6, d = fg & 63;
      #pragma unroll
      for (int j = 0; j < 4; ++j) {
        const int mg = m0 + wu * 64 + j * 16 + lrow;
        const int b = mg >> 10, n = mg & 1023;
        hbt[((size_t)(b * Hh + h) * DH + d) * Nn + n] = (short)f2bf(acc[i][j][r] + bv[r]);
      }
    }
  }
}

// ---------------- K3: s_src/s_dst from hbt ----------------
__global__ __launch_bounds__(256) void scores_kernel(const short* __restrict__ hbt,
                                                     const float* __restrict__ att,
                                                     float* __restrict__ ssrc,
                                                     float* __restrict__ sdst) {
  const int bh = blockIdx.y;                 // b*8 + h
  const int h = bh & 7;
  const int n = blockIdx.x * 256 + threadIdx.x;
  const short* base = hbt + (size_t)bh * DH * Nn + n;
  const float* as_ = att + h * 2 * DH;
  const float* ad_ = as_ + DH;
  float ps = 0.f, pd = 0.f;
  #pragma unroll
  for (int d = 0; d < DH; ++d) {
    const float v = bf2f((unsigned short)base[(size_t)d * Nn]);
    ps += v * as_[d];
    pd += v * ad_[d];
  }
  ssrc[(size_t)bh * Nn + n] = ps;
  sdst[(size_t)bh * Nn + n] = pd;
}

// ---------------- K4: fused masked-softmax attention + PV + ELU ----------------
// 8 waves split j-space in half; depth-1 software-pipelined loads (A/B register
// sets); denominator via MFMA against a bf16 ones-vector (row sums land at the
// owning lane, no shuffles). Partial acc/denoms combined through LDS.
struct PF {
  vfloat4 s0, s1;
  vint4   a0, a1;
  vshort8 v0, v1, v2, v3;
};

__device__ __forceinline__ PF loadPF(const float* __restrict__ ssp,
                                     const int* __restrict__ adjrow,
                                     const short* __restrict__ vb0,
                                     const short* __restrict__ vb1,
                                     const short* __restrict__ vb2,
                                     const short* __restrict__ vb3, int jb) {
  PF p;
  p.s0 = *(const vfloat4*)(ssp + jb);
  p.s1 = *(const vfloat4*)(ssp + jb + 4);
  p.a0 = *(const vint4*)(adjrow + jb);
  p.a1 = *(const vint4*)(adjrow + jb + 4);
  p.v0 = *(const vshort8*)(vb0 + jb);
  p.v1 = *(const vshort8*)(vb1 + jb);
  p.v2 = *(const vshort8*)(vb2 + jb);
  p.v3 = *(const vshort8*)(vb3 + jb);
  return p;
}

__device__ __forceinline__ void computePF(const PF& p, float sdi, vshort8 ones,
                                          vfloat4 acc[4], vfloat4& accd) {
  vshort8 af;
  #pragma unroll
  for (int e = 0; e < 4; ++e) {
    float tv = sdi + p.s0[e];
    tv = fmaxf(tv, LRELU_ALPHA * tv);                 // leaky_relu, alpha<1
    const float pe = (p.a0[e] > 0) ? __expf(tv) : 0.f; // logits bounded ~9, no max-sub
    af[e] = (short)__bfloat16_as_ushort(__float2bfloat16(pe));
  }
  #pragma unroll
  for (int e = 0; e < 4; ++e) {
    float tv = sdi + p.s1[e];
    tv = fmaxf(tv, LRELU_ALPHA * tv);
    const float pe = (p.a1[e] > 0) ? __expf(tv) : 0.f;
    af[4 + e] = (short)__bfloat16_as_ushort(__float2bfloat16(pe));
  }
  acc[0] = __builtin_amdgcn_mfma_f32_16x16x32_bf16(af, p.v0, acc[0], 0, 0, 0);
  acc[1] = __builtin_amdgcn_mfma_f32_16x16x32_bf16(af, p.v1, acc[1], 0, 0, 0);
  acc[2] = __builtin_amdgcn_mfma_f32_16x16x32_bf16(af, p.v2, acc[2], 0, 0, 0);
  acc[3] = __builtin_amdgcn_mfma_f32_16x16x32_bf16(af, p.v3, acc[3], 0, 0, 0);
  accd   = __builtin_amdgcn_mfma_f32_16x16x32_bf16(af, ones, accd, 0, 0, 0);
}

__global__ __launch_bounds__(512, 4) void attn_kernel(const int* __restrict__ adj,
                                                      const float* __restrict__ ssrc,
                                                      const float* __restrict__ sdst,
                                                      const short* __restrict__ hbt,
                                                      float* __restrict__ out) {
  __shared__ vfloat4 laccs[4][4][64];   // [df][iw][lane]
  __shared__ vfloat4 lsumv[4][64];
  const int it = blockIdx.x, h = blockIdx.y, b = blockIdx.z;
  const int tid = threadIdx.x;
  const int w = tid >> 6, l = tid & 63;
  const int iw = w & 3, jg = w >> 2;
  const int lrow = l & 15, lk = l >> 4;
  const int i = it * 64 + iw * 16 + lrow;          // query row owned by this lane
  const float sdi = sdst[(size_t)(b * Hh + h) * Nn + i];
  const float* ssp = ssrc + (size_t)(b * Hh + h) * Nn;
  const int* adjrow = adj + ((size_t)b * Nn + i) * Nn;
  const short* vb = hbt + (size_t)(b * Hh + h) * DH * Nn;
  const short* vb0 = vb + (size_t)(0 * 16 + lrow) * Nn;
  const short* vb1 = vb + (size_t)(1 * 16 + lrow) * Nn;
  const short* vb2 = vb + (size_t)(2 * 16 + lrow) * Nn;
  const short* vb3 = vb + (size_t)(3 * 16 + lrow) * Nn;
  vshort8 ones;
  #pragma unroll
  for (int e = 0; e < 8; ++e) ones[e] = (short)0x3F80;   // bf16 1.0
  vfloat4 acc[4] = {};
  vfloat4 accd = {};
  const int jbeg = jg * 512, jend = jbeg + 512;
  PF A = loadPF(ssp, adjrow, vb0, vb1, vb2, vb3, jbeg + lk * 8);
  for (int j0 = jbeg; j0 < jend; j0 += 64) {
    PF Bp = loadPF(ssp, adjrow, vb0, vb1, vb2, vb3, j0 + 32 + lk * 8);
    computePF(A, sdi, ones, acc, accd);
    const int jn = (j0 + 64 < jend) ? (j0 + 64 + lk * 8) : (jbeg + lk * 8); // branchless wrap
    A = loadPF(ssp, adjrow, vb0, vb1, vb2, vb3, jn);
    computePF(Bp, sdi, ones, acc, accd);
  }
  if (jg == 1) {
    #pragma unroll
    for (int df = 0; df < 4; ++df) laccs[df][iw][l] = acc[df];
    lsumv[iw][l] = accd;
  }
  __syncthreads();
  if (jg == 1) return;
  #pragma unroll
  for (int df = 0; df < 4; ++df) acc[df] = acc[df] + laccs[df][iw][l];
  accd = accd + lsumv[iw][l];
  #pragma unroll
  for (int r = 0; r < 4; ++r) {
    const int lr = lk * 4 + r;                       // local output row (C/D layout)
    const float inv = 1.0f / accd[r];                // row-sum lives on this lane
    const int row = it * 64 + iw * 16 + lr;
    #pragma unroll
    for (int df = 0; df < 4; ++df) {
      float v = acc[df][r] * inv;
      v = v > 0.f ? v : expm1f(v);                   // ELU (alpha=1)
      out[((size_t)(b * Nn + row)) * FOUT + h * DH + df * 16 + lrow] = v;
    }
  }
}

extern "C" void kernel_launch(void* const* d_in, const int* in_sizes, int n_in,
                              void* d_out, int out_size, void* d_ws, size_t ws_size,
                              hipStream_t stream) {
  const float* x   = (const float*)d_in[0];
  const int*   adj = (const int*)d_in[1];
  const float* W   = (const float*)d_in[2];
  const float* Wb  = (const float*)d_in[3];
  const float* att = (const float*)d_in[4];
  float* out = (float*)d_out;

  // Scratch plan:
  //   d_out (16 MB, fully overwritten by attn_kernel at the end):
  //     [0, 8 MB)   xb  = bf16 cast of x            (dead after gemm)
  //     [8, 8.5 MB) Wt  = bf16 W^T [fout][fin]      (dead after gemm)
  //   d_ws (8.5 MB used — stays well inside workspace):
  //     [0, 8 MB)   hbt = (x@W+b)^T as [b][h][d][n] bf16
  //     [8, 8.5 MB) ssrc, sdst (f32)
  short* xb  = (short*)d_out;
  short* Wt  = xb + (size_t)Mm * FIN;
  short* hbt = (short*)d_ws;
  float* ssrc = (float*)(hbt + (size_t)Bb * Hh * DH * Nn);
  float* sdst = ssrc + (size_t)Bb * Hh * Nn;

  cast_x_kernel<<<1024, 256, 0, stream>>>(x, xb, Mm * FIN);
  transpose_w_kernel<<<dim3(FOUT / 64, FIN / 64), 256, 0, stream>>>(W, Wt);
  gemm_t_kernel<<<dim3(Mm / 128, FOUT / 128), 256, 0, stream>>>(xb, Wt, Wb, hbt);
  scores_kernel<<<dim3(Nn / 256, Bb * Hh), 256, 0, stream>>>(hbt, att, ssrc, sdst);
  attn_kernel<<<dim3(Nn / 64, Hh, Bb), 512, 0, stream>>>(adj, ssrc, sdst, hbt, out);
}

// Round 7
// 151.031 us; speedup vs baseline: 1.3991x; 1.3740x over previous
//
#include <hip/hip_runtime.h>
#include <hip/hip_bf16.h>
#include <stdint.h>

typedef __attribute__((ext_vector_type(8))) short  vshort8;
typedef __attribute__((ext_vector_type(4))) float  vfloat4;
typedef __attribute__((ext_vector_type(4))) int    vint4;

static constexpr int Bb   = 8;
static constexpr int Nn   = 1024;
static constexpr int FIN  = 512;
static constexpr int FOUT = 512;
static constexpr int Hh   = 8;
static constexpr int DH   = 64;
static constexpr int Mm   = Bb * Nn;          // 8192
static constexpr float LRELU_ALPHA = 0.2f;

__device__ __forceinline__ unsigned short f2bf(float f) {
  union { float f; uint32_t u; } c; c.f = f;
  uint32_t r = c.u + 0x7fffu + ((c.u >> 16) & 1u);   // RNE
  return (unsigned short)(r >> 16);
}
__device__ __forceinline__ float bf2f(unsigned short s) {
  union { uint32_t u; float f; } c; c.u = ((uint32_t)s) << 16; return c.f;
}

// ---------------- K0: bit-pack adj, transposed: packed[(b*32+w)*1024 + i] ----
__global__ __launch_bounds__(256) void pack_adj_kernel(const int* __restrict__ adj,
                                                       unsigned* __restrict__ pt) {
  const int gid = blockIdx.x * 256 + threadIdx.x;   // 256K threads
  const int i = gid & 1023;
  const int w = (gid >> 10) & 31;
  const int b = gid >> 15;
  const int* src = adj + ((size_t)b * Nn + i) * Nn + w * 32;
  unsigned u = 0;
  #pragma unroll
  for (int e = 0; e < 32; ++e) u |= (src[e] > 0 ? 1u : 0u) << e;
  pt[gid] = u;
}

// ---------------- K1: cast x -> bf16 (into d_out scratch) ----------------
__global__ __launch_bounds__(256) void cast_x_kernel(const float* __restrict__ x,
                                                     short* __restrict__ xb, int n) {
  int i = (blockIdx.x * 256 + threadIdx.x) * 8;
  const int stride = gridDim.x * 256 * 8;
  for (; i < n; i += stride) {
    vfloat4 v0 = *(const vfloat4*)(x + i);
    vfloat4 v1 = *(const vfloat4*)(x + i + 4);
    vshort8 o;
    o[0] = (short)f2bf(v0[0]); o[1] = (short)f2bf(v0[1]);
    o[2] = (short)f2bf(v0[2]); o[3] = (short)f2bf(v0[3]);
    o[4] = (short)f2bf(v1[0]); o[5] = (short)f2bf(v1[1]);
    o[6] = (short)f2bf(v1[2]); o[7] = (short)f2bf(v1[3]);
    *(vshort8*)(xb + i) = o;
  }
}

// ---------------- K1b: W[k][n] -> Wt[n][k] bf16 (into d_out scratch) ------
__global__ __launch_bounds__(256) void transpose_w_kernel(const float* __restrict__ W,
                                                          short* __restrict__ Wt) {
  __shared__ float tile[64 * 65];
  const int n0 = blockIdx.x * 64, k0 = blockIdx.y * 64;
  const int c = threadIdx.x & 63, r4 = threadIdx.x >> 6;
  #pragma unroll
  for (int rr = 0; rr < 64; rr += 4)
    tile[(rr + r4) * 65 + c] = W[(size_t)(k0 + rr + r4) * FOUT + n0 + c];
  __syncthreads();
  #pragma unroll
  for (int rr = 0; rr < 64; rr += 4)
    Wt[(size_t)(n0 + rr + r4) * FIN + k0 + c] = (short)f2bf(tile[c * 65 + rr + r4]);
}

// ---------------- K2: hbt[b,h,d,n] = (xb @ W + bias)^T via swapped MFMA ---
__global__ __launch_bounds__(256) void gemm_t_kernel(const short* __restrict__ A,
                                                     const short* __restrict__ Bt,
                                                     const float* __restrict__ bias,
                                                     short* __restrict__ hbt) {
  __shared__ short As[128 * 64];
  __shared__ short Bs[128 * 64];
  const int tid = threadIdx.x;
  const int w = tid >> 6, l = tid & 63;
  const int wv = w >> 1;   // fout half of block tile
  const int wu = w & 1;    // m half of block tile
  const int lrow = l & 15, lk = l >> 4;
  const int m0 = blockIdx.x * 128, n0 = blockIdx.y * 128;
  vfloat4 acc[4][4] = {};
  for (int kt = 0; kt < FIN; kt += 64) {
    #pragma unroll
    for (int itr = 0; itr < 4; ++itr) {
      const int e = w * 2048 + itr * 512 + l * 8;
      const int row = e >> 6, col = e & 63;
      __builtin_amdgcn_global_load_lds(
          (const __attribute__((address_space(1))) unsigned int*)(A + (size_t)(m0 + row) * FIN + kt + col),
          (__attribute__((address_space(3))) unsigned int*)(As + w * 2048 + itr * 512),
          16, 0, 0);
      __builtin_amdgcn_global_load_lds(
          (const __attribute__((address_space(1))) unsigned int*)(Bt + (size_t)(n0 + row) * FIN + kt + col),
          (__attribute__((address_space(3))) unsigned int*)(Bs + w * 2048 + itr * 512),
          16, 0, 0);
    }
    __syncthreads();
    #pragma unroll
    for (int ks = 0; ks < 2; ++ks) {
      vshort8 af[4], bfr[4];
      #pragma unroll
      for (int i = 0; i < 4; ++i)   // A-operand of MFMA = Wt rows (fout dim)
        af[i] = *(const vshort8*)(Bs + (wv * 64 + i * 16 + lrow) * 64 + ks * 32 + lk * 8);
      #pragma unroll
      for (int j = 0; j < 4; ++j)   // B-operand of MFMA = x rows (m dim)
        bfr[j] = *(const vshort8*)(As + (wu * 64 + j * 16 + lrow) * 64 + ks * 32 + lk * 8);
      #pragma unroll
      for (int i = 0; i < 4; ++i)
        #pragma unroll
        for (int j = 0; j < 4; ++j)
          acc[i][j] = __builtin_amdgcn_mfma_f32_16x16x32_bf16(af[i], bfr[j], acc[i][j], 0, 0, 0);
    }
    __syncthreads();
  }
  #pragma unroll
  for (int i = 0; i < 4; ++i) {
    const int fbase = n0 + wv * 64 + i * 16 + lk * 4;
    const vfloat4 bv = *(const vfloat4*)(bias + fbase);
    #pragma unroll
    for (int r = 0; r < 4; ++r) {
      const int fg = fbase + r;
      const int h = fg >> 6, d = fg & 63;
      #pragma unroll
      for (int j = 0; j < 4; ++j) {
        const int mg = m0 + wu * 64 + j * 16 + lrow;
        const int b = mg >> 10, n = mg & 1023;
        hbt[((size_t)(b * Hh + h) * DH + d) * Nn + n] = (short)f2bf(acc[i][j][r] + bv[r]);
      }
    }
  }
}

// ---------------- K3: s_src/s_dst from hbt ----------------
__global__ __launch_bounds__(256) void scores_kernel(const short* __restrict__ hbt,
                                                     const float* __restrict__ att,
                                                     float* __restrict__ ssrc,
                                                     float* __restrict__ sdst) {
  const int bh = blockIdx.y;                 // b*8 + h
  const int h = bh & 7;
  const int n = blockIdx.x * 256 + threadIdx.x;
  const short* base = hbt + (size_t)bh * DH * Nn + n;
  const float* as_ = att + h * 2 * DH;
  const float* ad_ = as_ + DH;
  float ps = 0.f, pd = 0.f;
  #pragma unroll
  for (int d = 0; d < DH; ++d) {
    const float v = bf2f((unsigned short)base[(size_t)d * Nn]);
    ps += v * as_[d];
    pd += v * ad_[d];
  }
  ssrc[(size_t)bh * Nn + n] = ps;
  sdst[(size_t)bh * Nn + n] = pd;
}

// ---------------- K4: fused attention, LDS-staged V, packed adj ----------------
// 4 waves, 64 i-rows per block, all 1024 j. V-panel [64 d][128 j] double-buffered
// in LDS via global_load_lds with XOR swizzle (rule #21: inverse-swizzled global
// source + swizzled ds_read). Inner-loop VMEM = 4 gll + 4 adj words -> counted
// vmcnt(8) keeps next tile's loads in flight across barriers (T3/T4).
__device__ __forceinline__ void stage_vb(const short* __restrict__ vbbase,
                                         short* lds_buf, int iw, int l, int jt) {
  #pragma unroll
  for (int k = 0; k < 4; ++k) {
    const int d  = iw * 16 + k * 4 + (l >> 4);
    const int cs = (l & 15) * 16;                  // stored byte offset in row
    const int cd = cs ^ ((d & 7) << 4);            // inverse-swizzled data offset
    const int j  = jt + (cd >> 1);
    __builtin_amdgcn_global_load_lds(
        (const __attribute__((address_space(1))) unsigned int*)(vbbase + (size_t)d * Nn + j),
        (__attribute__((address_space(3))) unsigned int*)(lds_buf + iw * 2048 + k * 512),
        16, 0, 0);
  }
}

__global__ __launch_bounds__(256, 4) void attn_kernel(const unsigned* __restrict__ packed,
                                                      const float* __restrict__ ssrc,
                                                      const float* __restrict__ sdst,
                                                      const short* __restrict__ hbt,
                                                      float* __restrict__ out) {
  __shared__ short vbl[2][8192];     // 2 x 16 KB: [64 d][128 j] bf16, swizzled
  __shared__ float slds[1024];       // whole ssrc row for (b,h)
  const int it = blockIdx.x, h = blockIdx.y, b = blockIdx.z;
  const int tid = threadIdx.x;
  const int iw = tid >> 6, l = tid & 63;
  const int lrow = l & 15, lk = l >> 4;
  const int i = it * 64 + iw * 16 + lrow;          // query row owned by this lane
  const float sdi = sdst[(size_t)(b * Hh + h) * Nn + i];
  const float* ssp = ssrc + (size_t)(b * Hh + h) * Nn;
  const short* vbbase = hbt + (size_t)(b * Hh + h) * DH * Nn;
  const unsigned* ap = packed + (size_t)b * 32 * 1024 + i;   // word w at ap[w*1024]

  // prologue: stage ssrc row (1 gll/thread), tile 0 (4 gll), adj words tile 0
  __builtin_amdgcn_global_load_lds(
      (const __attribute__((address_space(1))) unsigned int*)(ssp + iw * 256 + l * 4),
      (__attribute__((address_space(3))) unsigned int*)(slds + iw * 256),
      16, 0, 0);
  stage_vb(vbbase, vbl[0], iw, l, 0);
  vint4 a_cur;
  #pragma unroll
  for (int s = 0; s < 4; ++s) a_cur[s] = (int)ap[s * 1024];
  asm volatile("s_waitcnt vmcnt(0)" ::: "memory");
  asm volatile("s_barrier" ::: "memory");

  vshort8 ones;
  #pragma unroll
  for (int e = 0; e < 8; ++e) ones[e] = (short)0x3F80;   // bf16 1.0
  vfloat4 acc[4] = {};
  vfloat4 accd = {};

  int buf = 0;
  for (int t = 0; t < 8; ++t) {
    vint4 a_nxt = {};
    if (t < 7) {
      stage_vb(vbbase, vbl[buf ^ 1], iw, l, (t + 1) * 128);   // 4 gll in flight
      #pragma unroll
      for (int s = 0; s < 4; ++s) a_nxt[s] = (int)ap[((t + 1) * 4 + s) * 1024];
      asm volatile("s_waitcnt vmcnt(8)" ::: "memory");        // cur tile's 8 done
    } else {
      asm volatile("s_waitcnt vmcnt(0)" ::: "memory");
    }
    asm volatile("s_barrier" ::: "memory");

    const char* vc = (const char*)vbl[buf];
    const char* sc = (const char*)slds + t * 512;
    #pragma unroll
    for (int s = 0; s < 4; ++s) {
      const vfloat4 s0 = *(const vfloat4*)(sc + s * 128 + lk * 32);
      const vfloat4 s1 = *(const vfloat4*)(sc + s * 128 + lk * 32 + 16);
      const unsigned u = ((unsigned)a_cur[s]) >> (lk * 8);
      vshort8 af;
      #pragma unroll
      for (int e = 0; e < 4; ++e) {
        float tv = sdi + s0[e];
        tv = fmaxf(tv, LRELU_ALPHA * tv);                    // leaky_relu
        const float pe = ((u >> e) & 1u) ? __expf(tv) : 0.f; // logits bounded, no max-sub
        af[e] = (short)__bfloat16_as_ushort(__float2bfloat16(pe));
      }
      #pragma unroll
      for (int e = 0; e < 4; ++e) {
        float tv = sdi + s1[e];
        tv = fmaxf(tv, LRELU_ALPHA * tv);
        const float pe = ((u >> (4 + e)) & 1u) ? __expf(tv) : 0.f;
        af[4 + e] = (short)__bfloat16_as_ushort(__float2bfloat16(pe));
      }
      const int cbase = (s * 64 + lk * 16) ^ ((lrow & 7) << 4);  // swizzled read
      vshort8 f0 = *(const vshort8*)(vc + (0 * 16 + lrow) * 256 + cbase);
      vshort8 f1 = *(const vshort8*)(vc + (1 * 16 + lrow) * 256 + cbase);
      vshort8 f2 = *(const vshort8*)(vc + (2 * 16 + lrow) * 256 + cbase);
      vshort8 f3 = *(const vshort8*)(vc + (3 * 16 + lrow) * 256 + cbase);
      acc[0] = __builtin_amdgcn_mfma_f32_16x16x32_bf16(af, f0, acc[0], 0, 0, 0);
      acc[1] = __builtin_amdgcn_mfma_f32_16x16x32_bf16(af, f1, acc[1], 0, 0, 0);
      acc[2] = __builtin_amdgcn_mfma_f32_16x16x32_bf16(af, f2, acc[2], 0, 0, 0);
      acc[3] = __builtin_amdgcn_mfma_f32_16x16x32_bf16(af, f3, acc[3], 0, 0, 0);
      accd   = __builtin_amdgcn_mfma_f32_16x16x32_bf16(af, ones, accd, 0, 0, 0);
    }
    if (t < 7) a_cur = a_nxt;
    asm volatile("s_barrier" ::: "memory");   // all waves done reading buf
    buf ^= 1;
  }

  #pragma unroll
  for (int r = 0; r < 4; ++r) {
    const int lr = lk * 4 + r;                       // D-layout local row
    const float inv = 1.0f / accd[r];                // row-sum lives on this lane
    const int row = it * 64 + iw * 16 + lr;
    #pragma unroll
    for (int df = 0; df < 4; ++df) {
      float v = acc[df][r] * inv;
      v = v > 0.f ? v : expm1f(v);                   // ELU (alpha=1)
      out[((size_t)(b * Nn + row)) * FOUT + h * DH + df * 16 + lrow] = v;
    }
  }
}

extern "C" void kernel_launch(void* const* d_in, const int* in_sizes, int n_in,
                              void* d_out, int out_size, void* d_ws, size_t ws_size,
                              hipStream_t stream) {
  const float* x   = (const float*)d_in[0];
  const int*   adj = (const int*)d_in[1];
  const float* W   = (const float*)d_in[2];
  const float* Wb  = (const float*)d_in[3];
  const float* att = (const float*)d_in[4];
  float* out = (float*)d_out;

  // Scratch plan:
  //   d_out (16 MB, fully overwritten by attn_kernel at the end):
  //     [0, 8 MB)    xb = bf16 x (dead after gemm); [8, 8.5 MB) Wt (dead after gemm)
  //   d_ws (9.5 MB used):
  //     [0, 8 MB)    hbt = (x@W+b)^T as [b][h][d][n] bf16
  //     [8, 8.5 MB)  ssrc, sdst (f32)
  //     [8.5,9.5 MB) packed adj bitmask, transposed [b][word][i]
  short* xb  = (short*)d_out;
  short* Wt  = xb + (size_t)Mm * FIN;
  short* hbt = (short*)d_ws;
  float* ssrc = (float*)(hbt + (size_t)Bb * Hh * DH * Nn);
  float* sdst = ssrc + (size_t)Bb * Hh * Nn;
  unsigned* packed = (unsigned*)(sdst + (size_t)Bb * Hh * Nn);

  pack_adj_kernel<<<1024, 256, 0, stream>>>(adj, packed);
  cast_x_kernel<<<1024, 256, 0, stream>>>(x, xb, Mm * FIN);
  transpose_w_kernel<<<dim3(FOUT / 64, FIN / 64), 256, 0, stream>>>(W, Wt);
  gemm_t_kernel<<<dim3(Mm / 128, FOUT / 128), 256, 0, stream>>>(xb, Wt, Wb, hbt);
  scores_kernel<<<dim3(Nn / 256, Bb * Hh), 256, 0, stream>>>(hbt, att, ssrc, sdst);
  attn_kernel<<<dim3(Nn / 64, Hh, Bb), 256, 0, stream>>>(packed, ssrc, sdst, hbt, out);
}

// Round 8
// 139.417 us; speedup vs baseline: 1.5157x; 1.0833x over previous
//
#include <hip/hip_runtime.h>
#include <hip/hip_bf16.h>
#include <stdint.h>

typedef __attribute__((ext_vector_type(8))) short  vshort8;
typedef __attribute__((ext_vector_type(4))) float  vfloat4;
typedef __attribute__((ext_vector_type(4))) int    vint4;

static constexpr int Bb   = 8;
static constexpr int Nn   = 1024;
static constexpr int FIN  = 512;
static constexpr int FOUT = 512;
static constexpr int Hh   = 8;
static constexpr int DH   = 64;
static constexpr int Mm   = Bb * Nn;          // 8192
static constexpr float LRELU_ALPHA = 0.2f;
static constexpr float LOG2E = 1.4426950408889634f;

__device__ __forceinline__ unsigned short f2bf(float f) {
  union { float f; uint32_t u; } c; c.f = f;
  uint32_t r = c.u + 0x7fffu + ((c.u >> 16) & 1u);   // RNE
  return (unsigned short)(r >> 16);
}
__device__ __forceinline__ float bf2f(unsigned short s) {
  union { uint32_t u; float f; } c; c.u = ((uint32_t)s) << 16; return c.f;
}

// ---------------- K0: fused prep: pack adj (ballot), cast x, transpose W ----
// grid: [0,2048) pack rows (4 rows/block), [2048,3072) cast, [3072,3136) transpose
__global__ __launch_bounds__(256) void prep_kernel(const int* __restrict__ adj,
                                                   const float* __restrict__ x,
                                                   const float* __restrict__ W,
                                                   unsigned* __restrict__ packed,
                                                   short* __restrict__ xb,
                                                   short* __restrict__ Wt) {
  __shared__ float tile[64 * 65];
  const int bx = blockIdx.x, tid = threadIdx.x;
  if (bx < 2048) {                       // ---- pack_adj: wave per row, ballot
    const int rowid = bx * 4 + (tid >> 6);
    const int b = rowid >> 10, i = rowid & 1023;
    const int l = tid & 63;
    const int* src = adj + (size_t)rowid * Nn;
    unsigned myw = 0;
    #pragma unroll
    for (int k = 0; k < 16; ++k) {
      const int v = src[k * 64 + l];                 // coalesced 256B/wave
      const unsigned long long m = __ballot(v > 0);
      if (l == 2 * k)     myw = (unsigned)m;
      if (l == 2 * k + 1) myw = (unsigned)(m >> 32);
    }
    if (l < 32) packed[((size_t)b * 32 + l) * 1024 + i] = myw;
  } else if (bx < 3072) {                // ---- cast x -> bf16
    int i = ((bx - 2048) * 256 + tid) * 8;
    const int stride = 1024 * 256 * 8;
    for (; i < Mm * FIN; i += stride) {
      vfloat4 v0 = *(const vfloat4*)(x + i);
      vfloat4 v1 = *(const vfloat4*)(x + i + 4);
      vshort8 o;
      o[0] = (short)f2bf(v0[0]); o[1] = (short)f2bf(v0[1]);
      o[2] = (short)f2bf(v0[2]); o[3] = (short)f2bf(v0[3]);
      o[4] = (short)f2bf(v1[0]); o[5] = (short)f2bf(v1[1]);
      o[6] = (short)f2bf(v1[2]); o[7] = (short)f2bf(v1[3]);
      *(vshort8*)(xb + i) = o;
    }
  } else {                               // ---- W[k][n] -> Wt[n][k] bf16
    const int bxx = bx - 3072;
    const int n0 = (bxx & 7) * 64, k0 = (bxx >> 3) * 64;
    const int c = tid & 63, r4 = tid >> 6;
    #pragma unroll
    for (int rr = 0; rr < 64; rr += 4)
      tile[(rr + r4) * 65 + c] = W[(size_t)(k0 + rr + r4) * FOUT + n0 + c];
    __syncthreads();
    #pragma unroll
    for (int rr = 0; rr < 64; rr += 4)
      Wt[(size_t)(n0 + rr + r4) * FIN + k0 + c] = (short)f2bf(tile[c * 65 + rr + r4]);
  }
}

// ---------------- K2: hbt[b,h,d,n] = (xb @ W + bias)^T, 64x64 tiles --------
// 1024 blocks (4/CU), 4 waves; wave w owns m-strip [m0+w*16,+16). XOR-swizzled
// LDS (rule #21: inverse-swizzled global source + swizzled ds_read_b128).
__global__ __launch_bounds__(256) void gemm_t_kernel(const short* __restrict__ A,
                                                     const short* __restrict__ Bt,
                                                     const float* __restrict__ bias,
                                                     short* __restrict__ hbt) {
  __shared__ short As[64 * 64];
  __shared__ short Bs[64 * 64];
  const int tid = threadIdx.x;
  const int w = tid >> 6, l = tid & 63;
  const int lrow = l & 15, lk = l >> 4;
  const int m0 = blockIdx.x * 64, n0 = blockIdx.y * 64;
  vfloat4 acc[4] = {};
  for (int kt = 0; kt < FIN; kt += 64) {
    #pragma unroll
    for (int p = 0; p < 2; ++p) {
      const int idxS = p * 2048 + tid * 8;           // linear LDS dest (shorts)
      const int row  = idxS >> 6;
      const int cs   = (idxS & 63) * 2;              // dest byte col
      const int cd   = cs ^ ((row & 7) << 4);        // inverse-swizzled src col
      __builtin_amdgcn_global_load_lds(
          (const __attribute__((address_space(1))) unsigned int*)(A + (size_t)(m0 + row) * FIN + kt + (cd >> 1)),
          (__attribute__((address_space(3))) unsigned int*)(As + idxS), 16, 0, 0);
      __builtin_amdgcn_global_load_lds(
          (const __attribute__((address_space(1))) unsigned int*)(Bt + (size_t)(n0 + row) * FIN + kt + (cd >> 1)),
          (__attribute__((address_space(3))) unsigned int*)(Bs + idxS), 16, 0, 0);
    }
    __syncthreads();
    #pragma unroll
    for (int ks = 0; ks < 2; ++ks) {
      const int mrow = w * 16 + lrow;
      const int gc   = ks * 64 + lk * 16;            // wanted byte col
      vshort8 bf = *(const vshort8*)((const char*)As + mrow * 128 + (gc ^ ((mrow & 7) << 4)));
      #pragma unroll
      for (int i = 0; i < 4; ++i) {
        const int frow = i * 16 + lrow;
        vshort8 af = *(const vshort8*)((const char*)Bs + frow * 128 + (gc ^ ((frow & 7) << 4)));
        acc[i] = __builtin_amdgcn_mfma_f32_16x16x32_bf16(af, bf, acc[i], 0, 0, 0);
      }
    }
    __syncthreads();
  }
  #pragma unroll
  for (int i = 0; i < 4; ++i) {
    const int fbase = n0 + i * 16 + lk * 4;
    const vfloat4 bv = *(const vfloat4*)(bias + fbase);
    #pragma unroll
    for (int r = 0; r < 4; ++r) {
      const int fg = fbase + r;
      const int h = fg >> 6, d = fg & 63;
      const int mg = m0 + w * 16 + lrow;
      const int b = mg >> 10, n = mg & 1023;
      hbt[((size_t)(b * Hh + h) * DH + d) * Nn + n] = (short)f2bf(acc[i][r] + bv[r]);
    }
  }
}

// ---------------- K3: s_src/s_dst (pre-scaled by log2e) from hbt ------------
// grid (4, 64): block = (n-quarter, b*h). 256 thr: 32 n-threads x 8 d-groups.
__global__ __launch_bounds__(256) void scores_kernel(const short* __restrict__ hbt,
                                                     const float* __restrict__ att,
                                                     float* __restrict__ ssrc,
                                                     float* __restrict__ sdst) {
  __shared__ float lps[8][32][8];
  __shared__ float lpd[8][32][8];
  const int bh = blockIdx.y, h = bh & 7;
  const int tid = threadIdx.x;
  const int tn = tid & 31, td = tid >> 5;
  const int n0 = blockIdx.x * 256 + tn * 8;
  const short* base = hbt + (size_t)bh * DH * Nn;
  float ps[8] = {}, pd[8] = {};
  #pragma unroll
  for (int dd = 0; dd < 8; ++dd) {
    const int d = td * 8 + dd;
    const vshort8 v = *(const vshort8*)(base + (size_t)d * Nn + n0);
    const float as_ = att[h * 2 * DH + d];
    const float ad_ = att[h * 2 * DH + DH + d];
    #pragma unroll
    for (int e = 0; e < 8; ++e) {
      const float f = bf2f((unsigned short)v[e]);
      ps[e] += f * as_;
      pd[e] += f * ad_;
    }
  }
  #pragma unroll
  for (int e = 0; e < 8; ++e) { lps[td][tn][e] = ps[e]; lpd[td][tn][e] = pd[e]; }
  __syncthreads();
  if (tid < 32) {
    float s[8] = {};
    #pragma unroll
    for (int q = 0; q < 8; ++q)
      #pragma unroll
      for (int e = 0; e < 8; ++e) s[e] += lps[q][tid][e];
    #pragma unroll
    for (int e = 0; e < 8; ++e) s[e] *= LOG2E;
    *(vfloat4*)(ssrc + (size_t)bh * Nn + blockIdx.x * 256 + tid * 8) = *(vfloat4*)s;
    *(vfloat4*)(ssrc + (size_t)bh * Nn + blockIdx.x * 256 + tid * 8 + 4) = *(vfloat4*)(s + 4);
  } else if (tid < 64) {
    const int t = tid - 32;
    float s[8] = {};
    #pragma unroll
    for (int q = 0; q < 8; ++q)
      #pragma unroll
      for (int e = 0; e < 8; ++e) s[e] += lpd[q][t][e];
    #pragma unroll
    for (int e = 0; e < 8; ++e) s[e] *= LOG2E;
    *(vfloat4*)(sdst + (size_t)bh * Nn + blockIdx.x * 256 + t * 8) = *(vfloat4*)s;
    *(vfloat4*)(sdst + (size_t)bh * Nn + blockIdx.x * 256 + t * 8 + 4) = *(vfloat4*)(s + 4);
  }
}

// ---------------- K4: fused attention, LDS-staged V, packed adj -------------
__device__ __forceinline__ void stage_vb(const short* __restrict__ vbbase,
                                         short* lds_buf, int iw, int l, int jt) {
  #pragma unroll
  for (int k = 0; k < 4; ++k) {
    const int d  = iw * 16 + k * 4 + (l >> 4);
    const int cs = (l & 15) * 16;                  // stored byte offset in row
    const int cd = cs ^ ((d & 7) << 4);            // inverse-swizzled data offset
    const int j  = jt + (cd >> 1);
    __builtin_amdgcn_global_load_lds(
        (const __attribute__((address_space(1))) unsigned int*)(vbbase + (size_t)d * Nn + j),
        (__attribute__((address_space(3))) unsigned int*)(lds_buf + iw * 2048 + k * 512),
        16, 0, 0);
  }
}

__global__ __launch_bounds__(256, 4) void attn_kernel(const unsigned* __restrict__ packed,
                                                      const float* __restrict__ ssrc,
                                                      const float* __restrict__ sdst,
                                                      const short* __restrict__ hbt,
                                                      float* __restrict__ out) {
  __shared__ short vbl[2][8192];     // 2 x 16 KB: [64 d][128 j] bf16, swizzled
  __shared__ float slds[1024];       // whole ssrc row for (b,h), pre-scaled
  const int it = blockIdx.x, h = blockIdx.y, b = blockIdx.z;
  const int tid = threadIdx.x;
  const int iw = tid >> 6, l = tid & 63;
  const int lrow = l & 15, lk = l >> 4;
  const int i = it * 64 + iw * 16 + lrow;          // query row owned by this lane
  const float sdi = sdst[(size_t)(b * Hh + h) * Nn + i];
  const float* ssp = ssrc + (size_t)(b * Hh + h) * Nn;
  const short* vbbase = hbt + (size_t)(b * Hh + h) * DH * Nn;
  const unsigned* ap = packed + (size_t)b * 32 * 1024 + i;   // word w at ap[w*1024]

  __builtin_amdgcn_global_load_lds(
      (const __attribute__((address_space(1))) unsigned int*)(ssp + iw * 256 + l * 4),
      (__attribute__((address_space(3))) unsigned int*)(slds + iw * 256),
      16, 0, 0);
  stage_vb(vbbase, vbl[0], iw, l, 0);
  vint4 a_cur;
  #pragma unroll
  for (int s = 0; s < 4; ++s) a_cur[s] = (int)ap[s * 1024];
  asm volatile("s_waitcnt vmcnt(0)" ::: "memory");
  asm volatile("s_barrier" ::: "memory");

  vshort8 ones;
  #pragma unroll
  for (int e = 0; e < 8; ++e) ones[e] = (short)0x3F80;   // bf16 1.0
  vfloat4 acc[4] = {};
  vfloat4 accd = {};

  int buf = 0;
  for (int t = 0; t < 8; ++t) {
    vint4 a_nxt = {};
    if (t < 7) {
      stage_vb(vbbase, vbl[buf ^ 1], iw, l, (t + 1) * 128);
      #pragma unroll
      for (int s = 0; s < 4; ++s) a_nxt[s] = (int)ap[((t + 1) * 4 + s) * 1024];
      asm volatile("s_waitcnt vmcnt(8)" ::: "memory");        // drains cur tile's 8
    } else {
      asm volatile("s_waitcnt vmcnt(0)" ::: "memory");
    }
    asm volatile("s_barrier" ::: "memory");

    const char* vc = (const char*)vbl[buf];
    const char* sc = (const char*)slds + t * 512;
    #pragma unroll
    for (int s = 0; s < 4; ++s) {
      const vfloat4 s0 = *(const vfloat4*)(sc + s * 128 + lk * 32);
      const vfloat4 s1 = *(const vfloat4*)(sc + s * 128 + lk * 32 + 16);
      const unsigned u = ((unsigned)a_cur[s]) >> (lk * 8);
      vshort8 af;
      #pragma unroll
      for (int e = 0; e < 4; ++e) {
        float tv = sdi + s0[e];
        tv = fmaxf(tv, LRELU_ALPHA * tv);                    // leaky_relu (log2 domain)
        const float pe = ((u >> e) & 1u) ? __builtin_amdgcn_exp2f(tv) : 0.f;
        af[e] = (short)__bfloat16_as_ushort(__float2bfloat16(pe));
      }
      #pragma unroll
      for (int e = 0; e < 4; ++e) {
        float tv = sdi + s1[e];
        tv = fmaxf(tv, LRELU_ALPHA * tv);
        const float pe = ((u >> (4 + e)) & 1u) ? __builtin_amdgcn_exp2f(tv) : 0.f;
        af[4 + e] = (short)__bfloat16_as_ushort(__float2bfloat16(pe));
      }
      const int cbase = (s * 64 + lk * 16) ^ ((lrow & 7) << 4);  // swizzled read
      vshort8 f0 = *(const vshort8*)(vc + (0 * 16 + lrow) * 256 + cbase);
      vshort8 f1 = *(const vshort8*)(vc + (1 * 16 + lrow) * 256 + cbase);
      vshort8 f2 = *(const vshort8*)(vc + (2 * 16 + lrow) * 256 + cbase);
      vshort8 f3 = *(const vshort8*)(vc + (3 * 16 + lrow) * 256 + cbase);
      acc[0] = __builtin_amdgcn_mfma_f32_16x16x32_bf16(af, f0, acc[0], 0, 0, 0);
      acc[1] = __builtin_amdgcn_mfma_f32_16x16x32_bf16(af, f1, acc[1], 0, 0, 0);
      acc[2] = __builtin_amdgcn_mfma_f32_16x16x32_bf16(af, f2, acc[2], 0, 0, 0);
      acc[3] = __builtin_amdgcn_mfma_f32_16x16x32_bf16(af, f3, acc[3], 0, 0, 0);
      accd   = __builtin_amdgcn_mfma_f32_16x16x32_bf16(af, ones, accd, 0, 0, 0);
    }
    if (t < 7) a_cur = a_nxt;
    asm volatile("s_barrier" ::: "memory");   // all waves done reading buf
    buf ^= 1;
  }

  #pragma unroll
  for (int r = 0; r < 4; ++r) {
    const int lr = lk * 4 + r;                       // D-layout local row
    const float inv = 1.0f / accd[r];                // row-sum lives on this lane
    const int row = it * 64 + iw * 16 + lr;
    #pragma unroll
    for (int df = 0; df < 4; ++df) {
      float v = acc[df][r] * inv;
      v = v > 0.f ? v : expm1f(v);                   // ELU (alpha=1)
      out[((size_t)(b * Nn + row)) * FOUT + h * DH + df * 16 + lrow] = v;
    }
  }
}

extern "C" void kernel_launch(void* const* d_in, const int* in_sizes, int n_in,
                              void* d_out, int out_size, void* d_ws, size_t ws_size,
                              hipStream_t stream) {
  const float* x   = (const float*)d_in[0];
  const int*   adj = (const int*)d_in[1];
  const float* W   = (const float*)d_in[2];
  const float* Wb  = (const float*)d_in[3];
  const float* att = (const float*)d_in[4];
  float* out = (float*)d_out;

  // Scratch plan:
  //   d_out (16 MB, fully overwritten by attn_kernel at the end):
  //     [0, 8 MB)    xb = bf16 x (dead after gemm); [8, 8.5 MB) Wt (dead after gemm)
  //   d_ws (9.5 MB used):
  //     [0, 8 MB)    hbt = (x@W+b)^T as [b][h][d][n] bf16
  //     [8, 8.5 MB)  ssrc, sdst (f32, pre-scaled by log2e)
  //     [8.5,9.5 MB) packed adj bitmask, transposed [b][word][i]
  short* xb  = (short*)d_out;
  short* Wt  = xb + (size_t)Mm * FIN;
  short* hbt = (short*)d_ws;
  float* ssrc = (float*)(hbt + (size_t)Bb * Hh * DH * Nn);
  float* sdst = ssrc + (size_t)Bb * Hh * Nn;
  unsigned* packed = (unsigned*)(sdst + (size_t)Bb * Hh * Nn);

  prep_kernel<<<3136, 256, 0, stream>>>(adj, x, W, packed, xb, Wt);
  gemm_t_kernel<<<dim3(Mm / 64, FOUT / 64), 256, 0, stream>>>(xb, Wt, Wb, hbt);
  scores_kernel<<<dim3(4, Bb * Hh), 256, 0, stream>>>(hbt, att, ssrc, sdst);
  attn_kernel<<<dim3(Nn / 64, Hh, Bb), 256, 0, stream>>>(packed, ssrc, sdst, hbt, out);
}

// Round 10
// 134.451 us; speedup vs baseline: 1.5717x; 1.0369x over previous
//
#include <hip/hip_runtime.h>
#include <hip/hip_bf16.h>
#include <stdint.h>

typedef __attribute__((ext_vector_type(8))) short  vshort8;
typedef __attribute__((ext_vector_type(4))) float  vfloat4;
typedef __attribute__((ext_vector_type(4))) int    vint4;

static constexpr int Bb   = 8;
static constexpr int Nn   = 1024;
static constexpr int FIN  = 512;
static constexpr int FOUT = 512;
static constexpr int Hh   = 8;
static constexpr int DH   = 64;
static constexpr int Mm   = Bb * Nn;          // 8192
static constexpr float LRELU_ALPHA = 0.2f;
static constexpr float LOG2E = 1.4426950408889634f;

__device__ __forceinline__ unsigned short f2bf(float f) {
  union { float f; uint32_t u; } c; c.f = f;
  uint32_t r = c.u + 0x7fffu + ((c.u >> 16) & 1u);   // RNE
  return (unsigned short)(r >> 16);
}
__device__ __forceinline__ float bf2f(unsigned short s) {
  union { uint32_t u; float f; } c; c.u = ((uint32_t)s) << 16; return c.f;
}

// ---------------- K0: fused prep: pack adj (ballot), cast x, transpose W ----
// grid: [0,2048) pack rows (4 rows/block), [2048,3072) cast, [3072,3136) transpose
__global__ __launch_bounds__(256) void prep_kernel(const int* __restrict__ adj,
                                                   const float* __restrict__ x,
                                                   const float* __restrict__ W,
                                                   unsigned* __restrict__ packed,
                                                   short* __restrict__ xb,
                                                   short* __restrict__ Wt) {
  __shared__ float tile[64 * 65];
  const int bx = blockIdx.x, tid = threadIdx.x;
  if (bx < 2048) {                       // ---- pack_adj: wave per row, ballot
    const int rowid = bx * 4 + (tid >> 6);
    const int b = rowid >> 10, i = rowid & 1023;
    const int l = tid & 63;
    const int* src = adj + (size_t)rowid * Nn;
    unsigned myw = 0;
    #pragma unroll
    for (int k = 0; k < 16; ++k) {
      const int v = src[k * 64 + l];                 // coalesced 256B/wave
      const unsigned long long m = __ballot(v > 0);
      if (l == 2 * k)     myw = (unsigned)m;
      if (l == 2 * k + 1) myw = (unsigned)(m >> 32);
    }
    if (l < 32) packed[((size_t)b * 32 + l) * 1024 + i] = myw;
  } else if (bx < 3072) {                // ---- cast x -> bf16
    int i = ((bx - 2048) * 256 + tid) * 8;
    const int stride = 1024 * 256 * 8;
    for (; i < Mm * FIN; i += stride) {
      vfloat4 v0 = *(const vfloat4*)(x + i);
      vfloat4 v1 = *(const vfloat4*)(x + i + 4);
      vshort8 o;
      o[0] = (short)f2bf(v0[0]); o[1] = (short)f2bf(v0[1]);
      o[2] = (short)f2bf(v0[2]); o[3] = (short)f2bf(v0[3]);
      o[4] = (short)f2bf(v1[0]); o[5] = (short)f2bf(v1[1]);
      o[6] = (short)f2bf(v1[2]); o[7] = (short)f2bf(v1[3]);
      *(vshort8*)(xb + i) = o;
    }
  } else {                               // ---- W[k][n] -> Wt[n][k] bf16
    const int bxx = bx - 3072;
    const int n0 = (bxx & 7) * 64, k0 = (bxx >> 3) * 64;
    const int c = tid & 63, r4 = tid >> 6;
    #pragma unroll
    for (int rr = 0; rr < 64; rr += 4)
      tile[(rr + r4) * 65 + c] = W[(size_t)(k0 + rr + r4) * FOUT + n0 + c];
    __syncthreads();
    #pragma unroll
    for (int rr = 0; rr < 64; rr += 4)
      Wt[(size_t)(n0 + rr + r4) * FIN + k0 + c] = (short)f2bf(tile[c * 65 + rr + r4]);
  }
}

// ---------------- K2: gemm + fused scores epilogue --------------------------
// hbt[b,h,d,n] = (xb @ W + bias)^T ; ssrc/sdst = (h . a_src/dst) * log2e.
// 64x64 tiles, 1024 blocks (4/CU), XOR-swizzled LDS, K double-buffered with
// counted vmcnt(4) so next tile's loads fly under current tile's MFMAs.
__device__ __forceinline__ void stage_ab(const short* __restrict__ A,
                                         const short* __restrict__ Bt,
                                         short* as, short* bs,
                                         int m0, int n0, int kt, int tid) {
  #pragma unroll
  for (int p = 0; p < 2; ++p) {
    const int idxS = p * 2048 + tid * 8;           // linear LDS dest (shorts)
    const int row  = idxS >> 6;
    const int cs   = (idxS & 63) * 2;              // dest byte col
    const int cd   = cs ^ ((row & 7) << 4);        // inverse-swizzled src col
    __builtin_amdgcn_global_load_lds(
        (const __attribute__((address_space(1))) unsigned int*)(A + (size_t)(m0 + row) * FIN + kt + (cd >> 1)),
        (__attribute__((address_space(3))) unsigned int*)(as + idxS), 16, 0, 0);
    __builtin_amdgcn_global_load_lds(
        (const __attribute__((address_space(1))) unsigned int*)(Bt + (size_t)(n0 + row) * FIN + kt + (cd >> 1)),
        (__attribute__((address_space(3))) unsigned int*)(bs + idxS), 16, 0, 0);
  }
}

__global__ __launch_bounds__(256) void gemm_t_kernel(const short* __restrict__ A,
                                                     const short* __restrict__ Bt,
                                                     const float* __restrict__ bias,
                                                     const float* __restrict__ att,
                                                     short* __restrict__ hbt,
                                                     float* __restrict__ ssrc,
                                                     float* __restrict__ sdst) {
  __shared__ short As[2][4096];
  __shared__ short Bs[2][4096];
  const int tid = threadIdx.x;
  const int w = tid >> 6, l = tid & 63;
  const int lrow = l & 15, lk = l >> 4;
  const int m0 = blockIdx.x * 64, n0 = blockIdx.y * 64;
  vfloat4 acc[4] = {};
  stage_ab(A, Bt, As[0], Bs[0], m0, n0, 0, tid);
  int buf = 0;
  for (int ktt = 0; ktt < 8; ++ktt) {
    if (ktt < 7) {
      stage_ab(A, Bt, As[buf ^ 1], Bs[buf ^ 1], m0, n0, (ktt + 1) * 64, tid);
      asm volatile("s_waitcnt vmcnt(4)" ::: "memory");   // cur tile's 4 done
    } else {
      asm volatile("s_waitcnt vmcnt(0)" ::: "memory");
    }
    asm volatile("s_barrier" ::: "memory");
    #pragma unroll
    for (int ks = 0; ks < 2; ++ks) {
      const int mrow = w * 16 + lrow;
      const int gc   = ks * 64 + lk * 16;            // wanted byte col
      vshort8 bf = *(const vshort8*)((const char*)As[buf] + mrow * 128 + (gc ^ ((mrow & 7) << 4)));
      #pragma unroll
      for (int i = 0; i < 4; ++i) {
        const int frow = i * 16 + lrow;
        vshort8 af = *(const vshort8*)((const char*)Bs[buf] + frow * 128 + (gc ^ ((frow & 7) << 4)));
        acc[i] = __builtin_amdgcn_mfma_f32_16x16x32_bf16(af, bf, acc[i], 0, 0, 0);
      }
    }
    asm volatile("s_barrier" ::: "memory");   // all waves done reading buf
    buf ^= 1;
  }
  // epilogue: hbt write + fused s_src/s_dst (n0-tile == one head)
  const int hh = n0 >> 6;
  const float* a_src = att + hh * 2 * DH;
  const float* a_dst = a_src + DH;
  const int mg = m0 + w * 16 + lrow;
  const int b = mg >> 10, n = mg & 1023;
  float ps = 0.f, pd = 0.f;
  #pragma unroll
  for (int i = 0; i < 4; ++i) {
    const int fbase = n0 + i * 16 + lk * 4;
    const vfloat4 bv = *(const vfloat4*)(bias + fbase);
    #pragma unroll
    for (int r = 0; r < 4; ++r) {
      const int fl = i * 16 + lk * 4 + r;            // fout-local in [0,64)
      const float hv = acc[i][r] + bv[r];
      ps += hv * a_src[fl];
      pd += hv * a_dst[fl];
      hbt[((size_t)(b * Hh + hh) * DH + fl) * Nn + n] = (short)f2bf(hv);
    }
  }
  ps += __shfl_xor(ps, 16); ps += __shfl_xor(ps, 32);
  pd += __shfl_xor(pd, 16); pd += __shfl_xor(pd, 32);
  if (l < 16) {                                      // lk==0 lane writes
    ssrc[(size_t)(b * Hh + hh) * Nn + n] = ps * LOG2E;
    sdst[(size_t)(b * Hh + hh) * Nn + n] = pd * LOG2E;
  }
}

// ---------------- K4: fused attention, LDS-staged V, packed adj -------------
__device__ __forceinline__ void stage_vb(const short* __restrict__ vbbase,
                                         short* lds_buf, int iw, int l, int jt) {
  #pragma unroll
  for (int k = 0; k < 4; ++k) {
    const int d  = iw * 16 + k * 4 + (l >> 4);
    const int cs = (l & 15) * 16;                  // stored byte offset in row
    const int cd = cs ^ ((d & 7) << 4);            // inverse-swizzled data offset
    const int j  = jt + (cd >> 1);
    __builtin_amdgcn_global_load_lds(
        (const __attribute__((address_space(1))) unsigned int*)(vbbase + (size_t)d * Nn + j),
        (__attribute__((address_space(3))) unsigned int*)(lds_buf + iw * 2048 + k * 512),
        16, 0, 0);
  }
}

__global__ __launch_bounds__(256, 4) void attn_kernel(const unsigned* __restrict__ packed,
                                                      const float* __restrict__ ssrc,
                                                      const float* __restrict__ sdst,
                                                      const short* __restrict__ hbt,
                                                      float* __restrict__ out) {
  __shared__ short vbl[2][8192];     // 2 x 16 KB: [64 d][128 j] bf16, swizzled
  __shared__ float slds[1024];       // whole ssrc row for (b,h), pre-scaled
  const int it = blockIdx.x, h = blockIdx.y, b = blockIdx.z;
  const int tid = threadIdx.x;
  const int iw = tid >> 6, l = tid & 63;
  const int lrow = l & 15, lk = l >> 4;
  const int i = it * 64 + iw * 16 + lrow;          // query row owned by this lane
  const float sdi = sdst[(size_t)(b * Hh + h) * Nn + i];
  const float* ssp = ssrc + (size_t)(b * Hh + h) * Nn;
  const short* vbbase = hbt + (size_t)(b * Hh + h) * DH * Nn;
  const unsigned* ap = packed + (size_t)b * 32 * 1024 + i;   // word w at ap[w*1024]

  __builtin_amdgcn_global_load_lds(
      (const __attribute__((address_space(1))) unsigned int*)(ssp + iw * 256 + l * 4),
      (__attribute__((address_space(3))) unsigned int*)(slds + iw * 256),
      16, 0, 0);
  stage_vb(vbbase, vbl[0], iw, l, 0);
  vint4 a_cur;
  #pragma unroll
  for (int s = 0; s < 4; ++s) a_cur[s] = (int)ap[s * 1024];
  asm volatile("s_waitcnt vmcnt(0)" ::: "memory");
  asm volatile("s_barrier" ::: "memory");

  vshort8 ones;
  #pragma unroll
  for (int e = 0; e < 8; ++e) ones[e] = (short)0x3F80;   // bf16 1.0
  vfloat4 acc[4] = {};
  vfloat4 accd = {};

  int buf = 0;
  for (int t = 0; t < 8; ++t) {
    vint4 a_nxt = {};
    if (t < 7) {
      stage_vb(vbbase, vbl[buf ^ 1], iw, l, (t + 1) * 128);
      #pragma unroll
      for (int s = 0; s < 4; ++s) a_nxt[s] = (int)ap[((t + 1) * 4 + s) * 1024];
      asm volatile("s_waitcnt vmcnt(8)" ::: "memory");        // drains cur tile's 8
    } else {
      asm volatile("s_waitcnt vmcnt(0)" ::: "memory");
    }
    asm volatile("s_barrier" ::: "memory");

    const char* vc = (const char*)vbl[buf];
    const char* sc = (const char*)slds + t * 512;
    #pragma unroll
    for (int s = 0; s < 4; ++s) {
      const vfloat4 s0 = *(const vfloat4*)(sc + s * 128 + lk * 32);
      const vfloat4 s1 = *(const vfloat4*)(sc + s * 128 + lk * 32 + 16);
      const unsigned u = ((unsigned)a_cur[s]) >> (lk * 8);
      vshort8 af;
      #pragma unroll
      for (int e = 0; e < 4; ++e) {
        float tv = sdi + s0[e];
        tv = fmaxf(tv, LRELU_ALPHA * tv);                    // leaky_relu (log2 domain)
        const float pe = ((u >> e) & 1u) ? __builtin_amdgcn_exp2f(tv) : 0.f;
        af[e] = (short)__bfloat16_as_ushort(__float2bfloat16(pe));
      }
      #pragma unroll
      for (int e = 0; e < 4; ++e) {
        float tv = sdi + s1[e];
        tv = fmaxf(tv, LRELU_ALPHA * tv);
        const float pe = ((u >> (4 + e)) & 1u) ? __builtin_amdgcn_exp2f(tv) : 0.f;
        af[4 + e] = (short)__bfloat16_as_ushort(__float2bfloat16(pe));
      }
      const int cbase = (s * 64 + lk * 16) ^ ((lrow & 7) << 4);  // swizzled read
      vshort8 f0 = *(const vshort8*)(vc + (0 * 16 + lrow) * 256 + cbase);
      vshort8 f1 = *(const vshort8*)(vc + (1 * 16 + lrow) * 256 + cbase);
      vshort8 f2 = *(const vshort8*)(vc + (2 * 16 + lrow) * 256 + cbase);
      vshort8 f3 = *(const vshort8*)(vc + (3 * 16 + lrow) * 256 + cbase);
      acc[0] = __builtin_amdgcn_mfma_f32_16x16x32_bf16(af, f0, acc[0], 0, 0, 0);
      acc[1] = __builtin_amdgcn_mfma_f32_16x16x32_bf16(af, f1, acc[1], 0, 0, 0);
      acc[2] = __builtin_amdgcn_mfma_f32_16x16x32_bf16(af, f2, acc[2], 0, 0, 0);
      acc[3] = __builtin_amdgcn_mfma_f32_16x16x32_bf16(af, f3, acc[3], 0, 0, 0);
      accd   = __builtin_amdgcn_mfma_f32_16x16x32_bf16(af, ones, accd, 0, 0, 0);
    }
    if (t < 7) a_cur = a_nxt;
    asm volatile("s_barrier" ::: "memory");   // all waves done reading buf
    buf ^= 1;
  }

  #pragma unroll
  for (int r = 0; r < 4; ++r) {
    const int lr = lk * 4 + r;                       // D-layout local row
    const float inv = 1.0f / accd[r];                // row-sum lives on this lane
    const int row = it * 64 + iw * 16 + lr;
    #pragma unroll
    for (int df = 0; df < 4; ++df) {
      float v = acc[df][r] * inv;
      v = v > 0.f ? v : expm1f(v);                   // ELU (alpha=1)
      out[((size_t)(b * Nn + row)) * FOUT + h * DH + df * 16 + lrow] = v;
    }
  }
}

extern "C" void kernel_launch(void* const* d_in, const int* in_sizes, int n_in,
                              void* d_out, int out_size, void* d_ws, size_t ws_size,
                              hipStream_t stream) {
  const float* x   = (const float*)d_in[0];
  const int*   adj = (const int*)d_in[1];
  const float* W   = (const float*)d_in[2];
  const float* Wb  = (const float*)d_in[3];
  const float* att = (const float*)d_in[4];
  float* out = (float*)d_out;

  // Scratch plan:
  //   d_out (16 MB, fully overwritten by attn_kernel at the end):
  //     [0, 8 MB)    xb = bf16 x (dead after gemm); [8, 8.5 MB) Wt (dead after gemm)
  //   d_ws (9.5 MB used):
  //     [0, 8 MB)    hbt = (x@W+b)^T as [b][h][d][n] bf16
  //     [8, 8.5 MB)  ssrc, sdst (f32, pre-scaled by log2e)
  //     [8.5,9.5 MB) packed adj bitmask, transposed [b][word][i]
  short* xb  = (short*)d_out;
  short* Wt  = xb + (size_t)Mm * FIN;
  short* hbt = (short*)d_ws;
  float* ssrc = (float*)(hbt + (size_t)Bb * Hh * DH * Nn);
  float* sdst = ssrc + (size_t)Bb * Hh * Nn;
  unsigned* packed = (unsigned*)(sdst + (size_t)Bb * Hh * Nn);

  prep_kernel<<<3136, 256, 0, stream>>>(adj, x, W, packed, xb, Wt);
  gemm_t_kernel<<<dim3(Mm / 64, FOUT / 64), 256, 0, stream>>>(xb, Wt, Wb, att, hbt, ssrc, sdst);
  attn_kernel<<<dim3(Nn / 64, Hh, Bb), 256, 0, stream>>>(packed, ssrc, sdst, hbt, out);
}